// Round 1
// baseline (1439.627 us; speedup 1.0000x reference)
//
#include <hip/hip_runtime.h>
#include <stdint.h>
#include <stddef.h>

#define S_LEN 2048
#define B_N   4096
#define T_N   10
#define NEG_INF_F (-10000.0f)

// broadcast within 16-lane group: src lane = (lane & 0x10) | P  (per 32-lane half)
template<int P>
__device__ __forceinline__ float bcastf(float v) {
    return __int_as_float(__builtin_amdgcn_ds_swizzle(__float_as_int(v), (P << 5) | 0x10));
}

static __device__ __forceinline__ int imin(int a, int b) { return a < b ? a : b; }

// ---------------- forward: 16 lanes per batch, lane t<10 owns next-tag t ----------------
__global__ void __launch_bounds__(256) viterbi_fwd(const float* __restrict__ feats,
                                                   const float* __restrict__ trans,
                                                   const int* __restrict__ lengths,
                                                   unsigned char* __restrict__ bp,   // [S][B] 8-byte slots, 10 nibbles used
                                                   int* __restrict__ bestlast,
                                                   float* __restrict__ score) {
    const int tid = threadIdx.x;
    const int t   = tid & 15;
    const int b   = blockIdx.x * 16 + (tid >> 4);
    const bool act = (t < T_N);
    const int len = lengths[b];

    float tr0=0.f,tr1=0.f,tr2=0.f,tr3=0.f,tr4=0.f,tr5=0.f,tr6=0.f,tr7=0.f,tr8=0.f,tr9=0.f,trs=0.f;
    if (act) {
        const float* tr = trans + t * T_N;
        tr0=tr[0]; tr1=tr[1]; tr2=tr[2]; tr3=tr[3]; tr4=tr[4];
        tr5=tr[5]; tr6=tr[6]; tr7=tr[7]; tr8=tr[8]; tr9=tr[9];
        trs = trans[9 * T_N + t];   // STOP row, entry t
    }

    float fvn  = (t == 8) ? 0.0f : NEG_INF_F;   // init: START_TAG=8
    float lastv = NEG_INF_F;

    auto ldfeat = [&](int s) -> float {
        float v = 0.0f;
        if (act && s < len) v = feats[((size_t)s * B_N + b) * T_N + t];
        return v;
    };

    auto step = [&](int s, float f) {
        // broadcast current fv (lane p holds fv[p]) to all lanes of the group
        float g0=bcastf<0>(fvn), g1=bcastf<1>(fvn), g2=bcastf<2>(fvn), g3=bcastf<3>(fvn), g4=bcastf<4>(fvn),
              g5=bcastf<5>(fvn), g6=bcastf<6>(fvn), g7=bcastf<7>(fvn), g8=bcastf<8>(fvn), g9=bcastf<9>(fvn);
        float c0=g0+tr0, c1=g1+tr1, c2=g2+tr2, c3=g3+tr3, c4=g4+tr4;
        float c5=g5+tr5, c6=g6+tr6, c7=g7+tr7, c8=g8+tr8, c9=g9+tr9;
        // exact max (value only on critical path; max3-friendly nesting)
        float m012 = fmaxf(fmaxf(c0,c1),c2);
        float m345 = fmaxf(fmaxf(c3,c4),c5);
        float m678 = fmaxf(fmaxf(c6,c7),c8);
        float m = fmaxf(fmaxf(fmaxf(m012,m345),m678),c9);
        // first-occurrence argmax = min index among entries equal to max
        int e0=(c0==m)?0:15, e1=(c1==m)?1:15, e2=(c2==m)?2:15, e3=(c3==m)?3:15, e4=(c4==m)?4:15;
        int e5=(c5==m)?5:15, e6=(c6==m)?6:15, e7=(c7==m)?7:15, e8=(c8==m)?8:15, e9=(c9==m)?9:15;
        int i0 = imin(imin(e0,e1),e2);
        int i1 = imin(imin(e3,e4),e5);
        int i2 = imin(imin(e6,e7),e8);
        int idx = imin(imin(imin(i0,i1),i2),e9);
        // pack pair of nibbles (even lane stores byte: tag t low, tag t+1 high)
        int nbr = __builtin_amdgcn_ds_swizzle(idx, 0x041F);   // lane ^ 1
        if (act && (t & 1) == 0) {
            bp[(((size_t)s * B_N + b) << 3) + (t >> 1)] = (unsigned char)(idx | (nbr << 4));
        }
        float nv = m + f;
        if (s == len - 1) lastv = nv;
        fvn = nv;
    };

    // software pipeline: prefetch feats 8 steps ahead (HBM latency ~900cy)
    float fp0 = ldfeat(0), fp1 = ldfeat(1), fp2 = ldfeat(2), fp3 = ldfeat(3);
    float fp4 = ldfeat(4), fp5 = ldfeat(5), fp6 = ldfeat(6), fp7 = ldfeat(7);

    for (int s0 = 0; s0 < len; s0 += 8) {
        {                       step(s0+0, fp0); fp0 = ldfeat(s0+8);  }
        if (s0+1 < len) {       step(s0+1, fp1); fp1 = ldfeat(s0+9);  }
        if (s0+2 < len) {       step(s0+2, fp2); fp2 = ldfeat(s0+10); }
        if (s0+3 < len) {       step(s0+3, fp3); fp3 = ldfeat(s0+11); }
        if (s0+4 < len) {       step(s0+4, fp4); fp4 = ldfeat(s0+12); }
        if (s0+5 < len) {       step(s0+5, fp5); fp5 = ldfeat(s0+13); }
        if (s0+6 < len) {       step(s0+6, fp6); fp6 = ldfeat(s0+14); }
        if (s0+7 < len) {       step(s0+7, fp7); fp7 = ldfeat(s0+15); }
    }

    // terminal: last_fv[t] + trans[STOP][t]; exact max + first argmax across the group
    float term = act ? (lastv + trs) : -3.0e38f;
    float u0=bcastf<0>(term), u1=bcastf<1>(term), u2=bcastf<2>(term), u3=bcastf<3>(term), u4=bcastf<4>(term),
          u5=bcastf<5>(term), u6=bcastf<6>(term), u7=bcastf<7>(term), u8=bcastf<8>(term), u9=bcastf<9>(term);
    float n012 = fmaxf(fmaxf(u0,u1),u2);
    float n345 = fmaxf(fmaxf(u3,u4),u5);
    float n678 = fmaxf(fmaxf(u6,u7),u8);
    float pm = fmaxf(fmaxf(fmaxf(n012,n345),n678),u9);
    int f0=(u0==pm)?0:15, f1=(u1==pm)?1:15, f2=(u2==pm)?2:15, f3=(u3==pm)?3:15, f4=(u4==pm)?4:15;
    int f5=(u5==pm)?5:15, f6=(u6==pm)?6:15, f7=(u7==pm)?7:15, f8=(u8==pm)?8:15, f9=(u9==pm)?9:15;
    int j0 = imin(imin(f0,f1),f2);
    int j1 = imin(imin(f3,f4),f5);
    int j2 = imin(imin(f6,f7),f8);
    int bidx = imin(imin(imin(j0,j1),j2),f9);

    if (t == 0) {
        score[b]    = pm;
        bestlast[b] = bidx;
    }
}

// ---------------- backtrack: lane = batch; loads are cur-independent (prefetchable) ----------------
__global__ void __launch_bounds__(256) viterbi_bt(const uint2* __restrict__ bptr,
                                                  const int* __restrict__ bestlast,
                                                  const int* __restrict__ lengths,
                                                  float* __restrict__ opaths) {
    const int b = blockIdx.x * 256 + threadIdx.x;
    const int len = lengths[b];
    int cur = bestlast[b];
    float* op = opaths + (size_t)b * S_LEN;

    uint2 wA[16], wB[16];

    auto preload = [&](uint2 (&W)[16], int c) {
        #pragma unroll
        for (int u = 0; u < 16; ++u) {
            int r = c * 16 + u + 1;              // row needed at j = c*16+u (r = j+1)
            uint2 v = make_uint2(0u, 0u);
            if (r < len) v = bptr[(size_t)r * B_N + b];   // used iff j < len-1 <=> r < len; r <= len-1 <= S-1
            W[u] = v;
        }
    };
    auto process = [&](uint2 (&W)[16], int c) {
        float buf[16];
        #pragma unroll
        for (int u = 15; u >= 0; --u) {
            int j = c * 16 + u;
            if (j < len - 1) {
                uint2 w = W[u];
                unsigned word = (cur < 8) ? w.x : w.y;
                cur = (int)((word >> ((cur * 4) & 31)) & 15u);
            }
            buf[u] = (j < len) ? (float)cur : 0.0f;
        }
        #pragma unroll
        for (int q = 0; q < 4; ++q) {
            *(float4*)(op + c * 16 + q * 4) =
                make_float4(buf[q*4+0], buf[q*4+1], buf[q*4+2], buf[q*4+3]);
        }
    };

    constexpr int NCH = S_LEN / 16;  // 128 chunks, processed high->low, double-buffered
    preload(wA, NCH - 1);
    for (int c = NCH - 1; c >= 1; c -= 2) {
        preload(wB, c - 1);
        process(wA, c);
        if (c - 2 >= 0) preload(wA, c - 2);
        process(wB, c - 1);
    }
}

extern "C" void kernel_launch(void* const* d_in, const int* in_sizes, int n_in,
                              void* d_out, int out_size, void* d_ws, size_t ws_size,
                              hipStream_t stream) {
    const float* feats   = (const float*)d_in[0];
    const float* trans   = (const float*)d_in[1];
    const int*   lengths = (const int*)d_in[2];
    float* out = (float*)d_out;

    // workspace: [S][B] 8-byte backpointer slots (67.1 MB) + bestlast[B]
    unsigned char* bp = (unsigned char*)d_ws;
    int* bestlast = (int*)((char*)d_ws + (size_t)S_LEN * B_N * 8);

    viterbi_fwd<<<B_N / 16, 256, 0, stream>>>(feats, trans, lengths, bp, bestlast, out);
    viterbi_bt<<<B_N / 256, 256, 0, stream>>>((const uint2*)d_ws, bestlast, lengths, out + B_N);
}

// Round 2
// 772.255 us; speedup vs baseline: 1.8642x; 1.8642x over previous
//
#include <hip/hip_runtime.h>
#include <stdint.h>
#include <stddef.h>

#define S_LEN 2048
#define B_N   4096
#define T_N   10
#define NEG_INF_F (-10000.0f)

// broadcast within 16-lane group: src lane = (lane & 0x10) | P  (per 32-lane half)
template<int P>
__device__ __forceinline__ float bcastf(float v) {
    return __int_as_float(__builtin_amdgcn_ds_swizzle(__float_as_int(v), (P << 5) | 0x10));
}

static __device__ __forceinline__ int imin(int a, int b) { return a < b ? a : b; }
static __device__ __forceinline__ int imax(int a, int b) { return a > b ? a : b; }

// ---------------- forward: 16 lanes per batch, lane t<10 owns next-tag t ----------------
__global__ void __launch_bounds__(256) viterbi_fwd(const float* __restrict__ feats,
                                                   const float* __restrict__ trans,
                                                   const int* __restrict__ lengths,
                                                   unsigned char* __restrict__ bp,   // [S][B] 8-byte slots, 10 nibbles used
                                                   int* __restrict__ bestlast,
                                                   float* __restrict__ score) {
    const int tid = threadIdx.x;
    const int t   = tid & 15;
    const int b   = blockIdx.x * 16 + (tid >> 4);
    const bool act = (t < T_N);
    const int len = lengths[b];

    // wave-uniform loop bound (len is uniform within each 16-lane group)
    int lenW = len;
    lenW = imax(lenW, __shfl_xor(lenW, 16, 64));
    lenW = imax(lenW, __shfl_xor(lenW, 32, 64));
    lenW = __builtin_amdgcn_readfirstlane(lenW);

    float tr0=0.f,tr1=0.f,tr2=0.f,tr3=0.f,tr4=0.f,tr5=0.f,tr6=0.f,tr7=0.f,tr8=0.f,tr9=0.f,trs=0.f;
    if (act) {
        const float* tr = trans + t * T_N;
        tr0=tr[0]; tr1=tr[1]; tr2=tr[2]; tr3=tr[3]; tr4=tr[4];
        tr5=tr[5]; tr6=tr[6]; tr7=tr[7]; tr8=tr[8]; tr9=tr[9];
        trs = trans[9 * T_N + t];   // STOP row, entry t
    }

    float fvn   = (t == 8) ? 0.0f : NEG_INF_F;   // init: START_TAG=8
    float lastv = NEG_INF_F;

    const float* fptr = feats + (size_t)b * T_N + t;   // + s*B*T walks rows
    auto ldfeat = [&](int s) -> float {
        float v = 0.0f;
        if (act && s < len) v = fptr[(size_t)s * (B_N * T_N)];
        return v;
    };

    float fA[8], fB[8];
    #pragma unroll
    for (int u = 0; u < 8; ++u) fA[u] = ldfeat(u);

    for (int s0 = 0; s0 < lenW; s0 += 8) {
        // (1) issue next block's loads — no deps on the step chain
        #pragma unroll
        for (int u = 0; u < 8; ++u) fB[u] = ldfeat(s0 + 8 + u);

        // (2) 8 steps: swizzle-broadcast + VALU only
        int idxs[8];
        #pragma unroll
        for (int u = 0; u < 8; ++u) {
            const int s = s0 + u;
            float g0=bcastf<0>(fvn), g1=bcastf<1>(fvn), g2=bcastf<2>(fvn), g3=bcastf<3>(fvn), g4=bcastf<4>(fvn),
                  g5=bcastf<5>(fvn), g6=bcastf<6>(fvn), g7=bcastf<7>(fvn), g8=bcastf<8>(fvn), g9=bcastf<9>(fvn);
            float c0=g0+tr0, c1=g1+tr1, c2=g2+tr2, c3=g3+tr3, c4=g4+tr4;
            float c5=g5+tr5, c6=g6+tr6, c7=g7+tr7, c8=g8+tr8, c9=g9+tr9;
            // exact max, max3-shaped (depth 3)
            float m1 = fmaxf(fmaxf(c0,c1),c2);
            float m2 = fmaxf(fmaxf(c3,c4),c5);
            float m3 = fmaxf(fmaxf(c6,c7),c8);
            float m  = fmaxf(fmaxf(fmaxf(m1,m2),m3),c9);
            // first-occurrence argmax = min index among entries equal to max (off value path)
            int e0=(c0==m)?0:15, e1=(c1==m)?1:15, e2=(c2==m)?2:15, e3=(c3==m)?3:15, e4=(c4==m)?4:15;
            int e5=(c5==m)?5:15, e6=(c6==m)?6:15, e7=(c7==m)?7:15, e8=(c8==m)?8:15, e9=(c9==m)?9:15;
            int i0 = imin(imin(e0,e1),e2);
            int i1 = imin(imin(e3,e4),e5);
            int i2 = imin(imin(e6,e7),e8);
            idxs[u] = imin(imin(imin(i0,i1),i2),e9);
            float nv = m + fA[u];
            lastv = (s == len - 1) ? nv : lastv;
            fvn = nv;
        }

        // (3) batched pack + store (one lgkm drain per 8 steps, off the fv chain)
        #pragma unroll
        for (int u = 0; u < 8; ++u) {
            int nbr = __builtin_amdgcn_ds_swizzle(idxs[u], 0x041F);   // lane ^ 1
            const int s = s0 + u;
            if (act && (t & 1) == 0 && s < len) {
                bp[(((size_t)s * B_N + b) << 3) + (t >> 1)] = (unsigned char)(idxs[u] | (nbr << 4));
            }
        }

        #pragma unroll
        for (int u = 0; u < 8; ++u) fA[u] = fB[u];
    }

    // terminal: last_fv[t] + trans[STOP][t]; exact max + first argmax across the group
    float term = act ? (lastv + trs) : -3.0e38f;
    float u0=bcastf<0>(term), u1=bcastf<1>(term), u2=bcastf<2>(term), u3=bcastf<3>(term), u4=bcastf<4>(term),
          u5=bcastf<5>(term), u6=bcastf<6>(term), u7=bcastf<7>(term), u8=bcastf<8>(term), u9=bcastf<9>(term);
    float n1 = fmaxf(fmaxf(u0,u1),u2);
    float n2 = fmaxf(fmaxf(u3,u4),u5);
    float n3 = fmaxf(fmaxf(u6,u7),u8);
    float pm = fmaxf(fmaxf(fmaxf(n1,n2),n3),u9);
    int f0=(u0==pm)?0:15, f1=(u1==pm)?1:15, f2=(u2==pm)?2:15, f3=(u3==pm)?3:15, f4=(u4==pm)?4:15;
    int f5=(u5==pm)?5:15, f6=(u6==pm)?6:15, f7=(u7==pm)?7:15, f8=(u8==pm)?8:15, f9=(u9==pm)?9:15;
    int j0 = imin(imin(f0,f1),f2);
    int j1 = imin(imin(f3,f4),f5);
    int j2 = imin(imin(f6,f7),f8);
    int bidx = imin(imin(imin(j0,j1),j2),f9);

    if (t == 0) {
        score[b]    = pm;
        bestlast[b] = bidx;
    }
}

// ---------------- backtrack: lane = batch; loads are cur-independent (prefetchable) ----------------
__global__ void __launch_bounds__(256) viterbi_bt(const uint2* __restrict__ bptr,
                                                  const int* __restrict__ bestlast,
                                                  const int* __restrict__ lengths,
                                                  float* __restrict__ opaths) {
    const int b = blockIdx.x * 256 + threadIdx.x;
    const int len = lengths[b];
    int cur = bestlast[b];
    float* op = opaths + (size_t)b * S_LEN;

    uint2 w0[16], w1[16], w2[16];

    auto preload = [&](uint2 (&W)[16], int c) {
        if (c < 0) return;
        #pragma unroll
        for (int u = 0; u < 16; ++u) {
            int r = c * 16 + u + 1;              // row needed at j = c*16+u (r = j+1)
            uint2 v = make_uint2(0u, 0u);
            if (r < len) v = bptr[(size_t)r * B_N + b];   // used iff j < len-1 <=> r < len
            W[u] = v;
        }
    };
    auto process = [&](uint2 (&W)[16], int c) {
        float buf[16];
        #pragma unroll
        for (int u = 15; u >= 0; --u) {
            int j = c * 16 + u;
            if (j < len - 1) {
                uint2 w = W[u];
                unsigned word = (cur < 8) ? w.x : w.y;
                cur = (int)((word >> ((cur * 4) & 31)) & 15u);
            }
            buf[u] = (j < len) ? (float)cur : 0.0f;
        }
        #pragma unroll
        for (int q = 0; q < 4; ++q) {
            *(float4*)(op + c * 16 + q * 4) =
                make_float4(buf[q*4+0], buf[q*4+1], buf[q*4+2], buf[q*4+3]);
        }
    };

    constexpr int NCH = S_LEN / 16;  // 128 chunks, processed high->low, triple-buffered
    preload(w0, NCH - 1);
    preload(w1, NCH - 2);
    for (int c = NCH - 1; c >= 0; c -= 3) {
        preload(w2, c - 2); process(w0, c);
        if (c - 1 < 0) break;
        preload(w0, c - 3); process(w1, c - 1);
        if (c - 2 < 0) break;
        preload(w1, c - 4); process(w2, c - 2);
    }
}

extern "C" void kernel_launch(void* const* d_in, const int* in_sizes, int n_in,
                              void* d_out, int out_size, void* d_ws, size_t ws_size,
                              hipStream_t stream) {
    const float* feats   = (const float*)d_in[0];
    const float* trans   = (const float*)d_in[1];
    const int*   lengths = (const int*)d_in[2];
    float* out = (float*)d_out;

    // workspace: [S][B] 8-byte backpointer slots (67.1 MB) + bestlast[B]
    unsigned char* bp = (unsigned char*)d_ws;
    int* bestlast = (int*)((char*)d_ws + (size_t)S_LEN * B_N * 8);

    viterbi_fwd<<<B_N / 16, 256, 0, stream>>>(feats, trans, lengths, bp, bestlast, out);
    viterbi_bt<<<B_N / 256, 256, 0, stream>>>((const uint2*)d_ws, bestlast, lengths, out + B_N);
}

// Round 3
// 556.644 us; speedup vs baseline: 2.5863x; 1.3873x over previous
//
#include <hip/hip_runtime.h>
#include <stdint.h>
#include <stddef.h>

#define S_LEN 2048
#define B_N   4096
#define T_N   10
#define NEG_INF_F (-10000.0f)

template<int CTRL>
__device__ __forceinline__ int dppi(int v) {
    return __builtin_amdgcn_update_dpp(0, v, CTRL, 0xF, 0xF, true);
}
template<int CTRL>
__device__ __forceinline__ float dppf(float v) {
    return __int_as_float(dppi<CTRL>(__float_as_int(v)));
}

static __device__ __forceinline__ int imin(int a, int b) { return a < b ? a : b; }
static __device__ __forceinline__ int imax(int a, int b) { return a > b ? a : b; }

// nibble-map apply: next = (w64 >> 4*cur) & 15
static __device__ __forceinline__ int bpapply(uint2 w, int cur) {
    unsigned long long w64 = ((unsigned long long)w.y << 32) | (unsigned long long)w.x;
    return (int)((w64 >> (cur * 4)) & 15ULL);
}

// ---------------- forward: 16 lanes per batch, lane t<10 owns next-tag t; DPP broadcasts ----------------
__global__ void __launch_bounds__(256) viterbi_fwd(const float* __restrict__ feats,
                                                   const float* __restrict__ trans,
                                                   const int* __restrict__ lengths,
                                                   unsigned char* __restrict__ bp,   // [S][B] 8-byte slots, 10 nibbles
                                                   int* __restrict__ bestlast,
                                                   float* __restrict__ score) {
    const float FNINF = __int_as_float(0xff800000);   // -inf
    const int tid = threadIdx.x;
    const int t   = tid & 15;
    const int b   = blockIdx.x * 16 + (tid >> 4);
    const bool act = (t < T_N);
    const int len = lengths[b];
    const int lenm1 = len - 1;

    // wave-uniform loop bound
    int lenW = len;
    lenW = imax(lenW, __shfl_xor(lenW, 16, 64));
    lenW = imax(lenW, __shfl_xor(lenW, 32, 64));
    lenW = __builtin_amdgcn_readfirstlane(lenW);

    // probe actual DPP ror source lanes (direction-agnostic)
    int q[16];
    q[0]  = t;
    q[1]  = dppi<0x121>(t);  q[2]  = dppi<0x122>(t);  q[3]  = dppi<0x123>(t);
    q[4]  = dppi<0x124>(t);  q[5]  = dppi<0x125>(t);  q[6]  = dppi<0x126>(t);
    q[7]  = dppi<0x127>(t);  q[8]  = dppi<0x128>(t);  q[9]  = dppi<0x129>(t);
    q[10] = dppi<0x12A>(t);  q[11] = dppi<0x12B>(t);  q[12] = dppi<0x12C>(t);
    q[13] = dppi<0x12D>(t);  q[14] = dppi<0x12E>(t);  q[15] = dppi<0x12F>(t);

    float trr[16], tv[16];
    int bitp[16];
    #pragma unroll
    for (int r = 0; r < 16; ++r) {
        bool v = act && (q[r] < T_N);
        trr[r] = v ? trans[t * T_N + q[r]] : FNINF;   // tr[t][p]
        tv[r]  = v ? 0.0f : FNINF;
        bitp[r] = 1 << q[r];
    }
    const float trs = act ? trans[9 * T_N + t] : 0.0f;   // STOP row entry t

    // pairing direction for nibble pack (probe ror1)
    const bool fw = (q[1] == ((t + 1) & 15));
    const bool storemask = act && ((t & 1) == (fw ? 0 : 1));

    float fvn   = (t == 8) ? 0.0f : NEG_INF_F;   // START_TAG=8
    float lastv = NEG_INF_F;

    const int tc = imin(t, T_N - 1);
    const float* fptr = feats + (size_t)b * T_N + tc;
    auto ldfeat = [&](int s) -> float {
        int sm = imin(s, lenm1);
        return fptr[(size_t)sm * (B_N * T_N)];
    };

    float fA[8], fB[8];
    #pragma unroll
    for (int u = 0; u < 8; ++u) fA[u] = ldfeat(u);

    auto step = [&](int s, float f) {
        float c0  = fvn              + trr[0];
        float c1  = dppf<0x121>(fvn) + trr[1];
        float c2  = dppf<0x122>(fvn) + trr[2];
        float c3  = dppf<0x123>(fvn) + trr[3];
        float c4  = dppf<0x124>(fvn) + trr[4];
        float c5  = dppf<0x125>(fvn) + trr[5];
        float c6  = dppf<0x126>(fvn) + trr[6];
        float c7  = dppf<0x127>(fvn) + trr[7];
        float c8  = dppf<0x128>(fvn) + trr[8];
        float c9  = dppf<0x129>(fvn) + trr[9];
        float c10 = dppf<0x12A>(fvn) + trr[10];
        float c11 = dppf<0x12B>(fvn) + trr[11];
        float c12 = dppf<0x12C>(fvn) + trr[12];
        float c13 = dppf<0x12D>(fvn) + trr[13];
        float c14 = dppf<0x12E>(fvn) + trr[14];
        float c15 = dppf<0x12F>(fvn) + trr[15];
        float x0 = fmaxf(fmaxf(c0,c1),c2);
        float x1 = fmaxf(fmaxf(c3,c4),c5);
        float x2 = fmaxf(fmaxf(c6,c7),c8);
        float x3 = fmaxf(fmaxf(c9,c10),c11);
        float x4 = fmaxf(fmaxf(c12,c13),c14);
        float x5 = fmaxf(fmaxf(x0,x1),c15);
        float x6 = fmaxf(fmaxf(x2,x3),x4);
        float m  = fmaxf(x5,x6);
        int b0=(c0==m)?bitp[0]:0,  b1=(c1==m)?bitp[1]:0,  b2=(c2==m)?bitp[2]:0,  b3=(c3==m)?bitp[3]:0;
        int b4=(c4==m)?bitp[4]:0,  b5=(c5==m)?bitp[5]:0,  b6=(c6==m)?bitp[6]:0,  b7=(c7==m)?bitp[7]:0;
        int b8=(c8==m)?bitp[8]:0,  b9=(c9==m)?bitp[9]:0,  b10=(c10==m)?bitp[10]:0, b11=(c11==m)?bitp[11]:0;
        int b12=(c12==m)?bitp[12]:0, b13=(c13==m)?bitp[13]:0, b14=(c14==m)?bitp[14]:0, b15=(c15==m)?bitp[15]:0;
        int o0 = (b0|b1)|b2, o1 = (b3|b4)|b5, o2 = (b6|b7)|b8, o3 = (b9|b10)|b11, o4 = (b12|b13)|b14;
        int bits = ((o0|o1)|(o2|o3)) | (o4|b15);
        int idx = __builtin_ctz(bits);
        int nbr = dppi<0x121>(idx);
        int byte = fw ? (idx | (nbr << 4)) : (nbr | (idx << 4));
        if (storemask && s < len) {
            bp[(((size_t)s * B_N + b) << 3) + (t >> 1)] = (unsigned char)byte;
        }
        float nv = m + f;
        lastv = (s == lenm1) ? nv : lastv;
        fvn = nv;
    };

    for (int s0 = 0; s0 < lenW; s0 += 8) {
        #pragma unroll
        for (int u = 0; u < 8; ++u) fB[u] = ldfeat(s0 + 8 + u);
        #pragma unroll
        for (int u = 0; u < 8; ++u) step(s0 + u, fA[u]);
        #pragma unroll
        for (int u = 0; u < 8; ++u) fA[u] = fB[u];
    }

    // terminal: term[p] = last_fv[p] + trans[STOP][p]
    float term = lastv + trs;
    float c0  = term              + tv[0];
    float c1  = dppf<0x121>(term) + tv[1];
    float c2  = dppf<0x122>(term) + tv[2];
    float c3  = dppf<0x123>(term) + tv[3];
    float c4  = dppf<0x124>(term) + tv[4];
    float c5  = dppf<0x125>(term) + tv[5];
    float c6  = dppf<0x126>(term) + tv[6];
    float c7  = dppf<0x127>(term) + tv[7];
    float c8  = dppf<0x128>(term) + tv[8];
    float c9  = dppf<0x129>(term) + tv[9];
    float c10 = dppf<0x12A>(term) + tv[10];
    float c11 = dppf<0x12B>(term) + tv[11];
    float c12 = dppf<0x12C>(term) + tv[12];
    float c13 = dppf<0x12D>(term) + tv[13];
    float c14 = dppf<0x12E>(term) + tv[14];
    float c15 = dppf<0x12F>(term) + tv[15];
    float x0 = fmaxf(fmaxf(c0,c1),c2);
    float x1 = fmaxf(fmaxf(c3,c4),c5);
    float x2 = fmaxf(fmaxf(c6,c7),c8);
    float x3 = fmaxf(fmaxf(c9,c10),c11);
    float x4 = fmaxf(fmaxf(c12,c13),c14);
    float pm = fmaxf(fmaxf(fmaxf(fmaxf(x0,x1),c15), fmaxf(x2,x3)), x4);
    int e0=(c0==pm)?bitp[0]:0,  e1=(c1==pm)?bitp[1]:0,  e2=(c2==pm)?bitp[2]:0,  e3=(c3==pm)?bitp[3]:0;
    int e4=(c4==pm)?bitp[4]:0,  e5=(c5==pm)?bitp[5]:0,  e6=(c6==pm)?bitp[6]:0,  e7=(c7==pm)?bitp[7]:0;
    int e8=(c8==pm)?bitp[8]:0,  e9=(c9==pm)?bitp[9]:0,  e10=(c10==pm)?bitp[10]:0, e11=(c11==pm)?bitp[11]:0;
    int e12=(c12==pm)?bitp[12]:0, e13=(c13==pm)?bitp[13]:0, e14=(c14==pm)?bitp[14]:0, e15=(c15==pm)?bitp[15]:0;
    int bits = (((e0|e1)|e2) | ((e3|e4)|e5)) | (((e6|e7)|e8) | ((e9|e10)|e11)) | (((e12|e13)|e14) | e15);
    int bidx = __builtin_ctz(bits);

    if (t == 0) {
        score[b]    = pm;
        bestlast[b] = bidx;
    }
}

// ---------------- bt phase A: per (batch, 16-step chunk) compose map for all 10 entry tags ----------------
__global__ void __launch_bounds__(256) bt_maps(const uint2* __restrict__ bptr,
                                               const int* __restrict__ lengths,
                                               uint2* __restrict__ gmap) {
    const int c = blockIdx.x >> 4;                          // 0..127
    const int b = ((blockIdx.x & 15) << 8) + threadIdx.x;   // 0..4095
    const int len = lengths[b];
    const int r0 = c * 16 + 1;

    uint2 W[16];
    #pragma unroll
    for (int u = 0; u < 16; ++u) {
        int r = r0 + u;
        uint2 v = make_uint2(0x76543210u, 0x00000098u);     // identity map
        if (r < len) v = bptr[(size_t)r * B_N + b];
        W[u] = v;
    }

    unsigned gx = 0, gy = 0;
    #pragma unroll
    for (int e = 0; e < T_N; ++e) {
        int cur = e;
        #pragma unroll
        for (int u = 15; u >= 0; --u) cur = bpapply(W[u], cur);
        if (e < 8) gx |= (unsigned)cur << (4 * e);
        else       gy |= (unsigned)cur << (4 * (e - 8));
    }
    gmap[(size_t)c * B_N + b] = make_uint2(gx, gy);
}

// ---------------- bt phase B: compose 128 chunk maps per batch, record entry tag per chunk ----------------
__global__ void __launch_bounds__(256) bt_compose(const uint2* __restrict__ gmap,
                                                  const int* __restrict__ bestlast,
                                                  unsigned char* __restrict__ entry) {
    const int b = blockIdx.x * 256 + threadIdx.x;
    int st = bestlast[b];

    uint2 wA[16], wB[16];
    auto pre = [&](uint2 (&W)[16], int cb) {
        #pragma unroll
        for (int u = 0; u < 16; ++u) W[u] = gmap[(size_t)(cb * 16 + u) * B_N + b];
    };
    auto proc = [&](uint2 (&W)[16], int cb) {
        #pragma unroll
        for (int u = 15; u >= 0; --u) {
            int c = cb * 16 + u;
            entry[(size_t)c * B_N + b] = (unsigned char)st;
            st = bpapply(W[u], st);
        }
    };
    pre(wA, 7);
    pre(wB, 6); proc(wA, 7);
    pre(wA, 5); proc(wB, 6);
    pre(wB, 4); proc(wA, 5);
    pre(wA, 3); proc(wB, 4);
    pre(wB, 2); proc(wA, 3);
    pre(wA, 1); proc(wB, 2);
    pre(wB, 0); proc(wA, 1);
    proc(wB, 0);
}

// ---------------- bt phase C: per (batch, chunk) re-follow 16 steps from entry tag, emit path ----------------
__global__ void __launch_bounds__(256) bt_emit(const uint2* __restrict__ bptr,
                                               const int* __restrict__ lengths,
                                               const unsigned char* __restrict__ entry,
                                               float* __restrict__ opaths) {
    const int c = blockIdx.x >> 4;
    const int b = ((blockIdx.x & 15) << 8) + threadIdx.x;
    const int len = lengths[b];
    const int r0 = c * 16 + 1;

    uint2 W[16];
    #pragma unroll
    for (int u = 0; u < 16; ++u) {
        int r = r0 + u;
        uint2 v = make_uint2(0x76543210u, 0x00000098u);
        if (r < len) v = bptr[(size_t)r * B_N + b];
        W[u] = v;
    }

    int cur = entry[(size_t)c * B_N + b];
    float buf[16];
    #pragma unroll
    for (int u = 15; u >= 0; --u) {
        cur = bpapply(W[u], cur);
        buf[u] = (c * 16 + u < len) ? (float)cur : 0.0f;
    }
    float* op = opaths + (size_t)b * S_LEN + c * 16;
    #pragma unroll
    for (int qq = 0; qq < 4; ++qq) {
        *(float4*)(op + qq * 4) = make_float4(buf[qq*4+0], buf[qq*4+1], buf[qq*4+2], buf[qq*4+3]);
    }
}

extern "C" void kernel_launch(void* const* d_in, const int* in_sizes, int n_in,
                              void* d_out, int out_size, void* d_ws, size_t ws_size,
                              hipStream_t stream) {
    const float* feats   = (const float*)d_in[0];
    const float* trans   = (const float*)d_in[1];
    const int*   lengths = (const int*)d_in[2];
    float* out = (float*)d_out;

    // workspace layout
    unsigned char* bp    = (unsigned char*)d_ws;                                   // 67,108,864 B
    uint2*         gmap  = (uint2*)((char*)d_ws + (size_t)S_LEN * B_N * 8);        //  4,194,304 B
    unsigned char* entry = (unsigned char*)((char*)gmap + (size_t)(S_LEN/16) * B_N * 8); // 524,288 B
    int*           bestlast = (int*)((char*)entry + (size_t)(S_LEN/16) * B_N);     //     16,384 B

    viterbi_fwd<<<B_N / 16, 256, 0, stream>>>(feats, trans, lengths, bp, bestlast, out);
    bt_maps   <<<(S_LEN/16) * (B_N/256), 256, 0, stream>>>((const uint2*)bp, lengths, gmap);
    bt_compose<<<B_N / 256, 256, 0, stream>>>(gmap, bestlast, entry);
    bt_emit   <<<(S_LEN/16) * (B_N/256), 256, 0, stream>>>((const uint2*)bp, lengths, entry, out + B_N);
}

// Round 4
// 523.387 us; speedup vs baseline: 2.7506x; 1.0635x over previous
//
#include <hip/hip_runtime.h>
#include <stdint.h>
#include <stddef.h>

#define S_LEN 2048
#define B_N   4096
#define T_N   10
#define NEG_INF_F (-10000.0f)

template<int CTRL>
__device__ __forceinline__ int dppi(int v) {
    return __builtin_amdgcn_update_dpp(0, v, CTRL, 0xF, 0xF, true);
}
template<int CTRL>
__device__ __forceinline__ float dppf(float v) {
    return __int_as_float(dppi<CTRL>(__float_as_int(v)));
}

static __device__ __forceinline__ int imin(int a, int b) { return a < b ? a : b; }
static __device__ __forceinline__ int imax(int a, int b) { return a > b ? a : b; }
static __device__ __forceinline__ float fmax3(float a, float b, float c) { return fmaxf(fmaxf(a, b), c); }

// exchange 32-lane halves between x and y (gfx950 VALU cross-lane, no LDS pipe)
__device__ __forceinline__ void rowswap32(int &x, int &y) {
#if __has_builtin(__builtin_amdgcn_permlane32_swap)
    typedef unsigned u2 __attribute__((ext_vector_type(2)));
    u2 r = __builtin_amdgcn_permlane32_swap((unsigned)x, (unsigned)y, false, false);
    x = (int)r[0]; y = (int)r[1];
#else
    asm("v_permlane32_swap_b32 %0, %1" : "+v"(x), "+v"(y));
#endif
}

// nibble-map apply: next = (w64 >> 4*cur) & 15
static __device__ __forceinline__ int bpapply(uint2 w, int cur) {
    unsigned long long w64 = ((unsigned long long)w.y << 32) | (unsigned long long)w.x;
    return (int)((w64 >> (cur * 4)) & 15ULL);
}

// ---------------- forward: 32 lanes per batch (2 rows x 16 tags, preds split 8+8) ----------------
// lanes 0-31 = row A (preds 0-7) of batches {bb=0,bb=1}; lanes 32-63 = row B (preds 8-15)
__global__ void __launch_bounds__(256) viterbi_fwd(const float* __restrict__ feats,
                                                   const float* __restrict__ trans,
                                                   const int* __restrict__ lengths,
                                                   unsigned char* __restrict__ bp,   // [S][B] 8-byte slots
                                                   int* __restrict__ bestlast,
                                                   float* __restrict__ score) {
    const float FNINF = __int_as_float(0xff800000);   // -inf
    const int tid  = threadIdx.x;
    const int lane = tid & 63;
    const int c    = lane & 15;          // tag (column)
    const int bb   = (lane >> 4) & 1;    // batch within wave
    const int h    = lane >> 5;          // pred-half: 0 -> p in 0..7, 1 -> p in 8..15
    const int b    = blockIdx.x * 8 + ((tid >> 6) << 1) + bb;
    const int len  = lengths[b];
    const int lenm1 = len - 1;

    int lenW = len;
    lenW = imax(lenW, __shfl_xor(lenW, 16, 64));
    lenW = imax(lenW, __shfl_xor(lenW, 32, 64));
    lenW = __builtin_amdgcn_readfirstlane(lenW);

    // probe actual ror source columns (direction-agnostic)
    int q[16];
    q[0]  = c;
    q[1]  = dppi<0x121>(c);  q[2]  = dppi<0x122>(c);  q[3]  = dppi<0x123>(c);
    q[4]  = dppi<0x124>(c);  q[5]  = dppi<0x125>(c);  q[6]  = dppi<0x126>(c);
    q[7]  = dppi<0x127>(c);  q[8]  = dppi<0x128>(c);  q[9]  = dppi<0x129>(c);
    q[10] = dppi<0x12A>(c);  q[11] = dppi<0x12B>(c);  q[12] = dppi<0x12C>(c);
    q[13] = dppi<0x12D>(c);  q[14] = dppi<0x12E>(c);  q[15] = dppi<0x12F>(c);

    // per-lane tables: rotation r delivers fv[p_r], p_r = h*8 + (q_r & 7)
    float trr[8]; int pbit[8];
    #pragma unroll
    for (int r = 0; r < 8; ++r) {
        int pr = h * 8 + (q[r] & 7);
        bool valid = (c < T_N) && (pr < T_N);
        trr[r] = valid ? trans[c * T_N + pr] : FNINF;
        pbit[r] = 1 << pr;
    }
    const float trs = (c < T_N) ? trans[9 * T_N + c] : FNINF;

    // byte-pack pairing (probe ror:1 direction)
    const bool fw = (q[1] == ((c + 1) & 15));
    const bool storemask = (h == 0) && (c < T_N) && ((c & 1) == (fw ? 0 : 1));
    const unsigned sb32 = (unsigned)(b * 8 + ((fw ? c : c - 1) >> 1));
    const bool sel = ((((c >> 3) & 1) ^ h) != 0);   // fv re-skew select

    const int p0 = h * 8 + (c & 7);
    float fvr   = (p0 == 8) ? 0.0f : NEG_INF_F;   // START_TAG=8
    float lastv = NEG_INF_F;

    const unsigned fb32 = (unsigned)(b * T_N + imin(c, T_N - 1));
    auto ldfeat = [&](int s) -> float {
        unsigned sm = (unsigned)imin(s, S_LEN - 1);
        return feats[(size_t)sm * (unsigned)(B_N * T_N) + fb32];
    };

    float fA[8], fB[8];
    #pragma unroll
    for (int u = 0; u < 8; ++u) fA[u] = ldfeat(u);

    int idxs[8];
    for (int s0 = 0; s0 < lenW; s0 += 8) {
        #pragma unroll
        for (int u = 0; u < 8; ++u) fB[u] = ldfeat(s0 + 8 + u);

        #pragma unroll
        for (int u = 0; u < 8; ++u) {
            const int s = s0 + u;
            float c0 = fvr              + trr[0];
            float c1 = dppf<0x121>(fvr) + trr[1];
            float c2 = dppf<0x122>(fvr) + trr[2];
            float c3 = dppf<0x123>(fvr) + trr[3];
            float c4 = dppf<0x124>(fvr) + trr[4];
            float c5 = dppf<0x125>(fvr) + trr[5];
            float c6 = dppf<0x126>(fvr) + trr[6];
            float c7 = dppf<0x127>(fvr) + trr[7];
            // partial max over this half's 8 preds (max3-shaped)
            float m = fmax3(fmax3(c0, c1, c2), fmax3(c3, c4, c5), fmaxf(c6, c7));
            // cross-row merge: value
            int mi = __float_as_int(m), mj = mi;
            rowswap32(mi, mj);
            float mm = fmaxf(__int_as_float(mi), __int_as_float(mj));
            // equality bitmask vs FULL max (order-agnostic, first-occurrence = min p via ctz)
            int e0 = (c0 == mm) ? pbit[0] : 0;
            int e1 = (c1 == mm) ? pbit[1] : 0;
            int e2 = (c2 == mm) ? pbit[2] : 0;
            int e3 = (c3 == mm) ? pbit[3] : 0;
            int e4 = (c4 == mm) ? pbit[4] : 0;
            int e5 = (c5 == mm) ? pbit[5] : 0;
            int e6 = (c6 == mm) ? pbit[6] : 0;
            int e7 = (c7 == mm) ? pbit[7] : 0;
            int bits = ((e0 | e1 | e2) | (e3 | e4 | e5)) | (e6 | e7);
            int bj = bits;
            rowswap32(bits, bj);
            bits |= bj;
            idxs[u] = __builtin_ctz(bits);
            // new fv value for tag c (identical at all copies)
            float nv = mm + fA[u];
            lastv = (s == lenm1) ? nv : lastv;
            // re-skew: lane wants nv of col h*8 + (c&7) -> self or ror:8
            float t8 = dppf<0x128>(nv);
            fvr = sel ? t8 : nv;
        }

        // batched bp byte stores (DPP at full exec, single divergence per superstep)
        int bytes[8];
        #pragma unroll
        for (int u = 0; u < 8; ++u) {
            int nbr = dppi<0x121>(idxs[u]);
            bytes[u] = fw ? (idxs[u] | (nbr << 4)) : (nbr | (idxs[u] << 4));
        }
        if (storemask) {
            #pragma unroll
            for (int u = 0; u < 8; ++u) {
                unsigned sm = (unsigned)imin(s0 + u, S_LEN - 1);   // tail rows >= len are never read
                bp[((size_t)sm << 15) + sb32] = (unsigned char)bytes[u];
            }
        }

        #pragma unroll
        for (int u = 0; u < 8; ++u) fA[u] = fB[u];
    }

    // terminal: term[tag] = last_fv[tag] + trans[STOP][tag]; reduce across the 16-lane row
    float term = lastv + trs;   // -inf for c>=10
    float t1  = dppf<0x121>(term), t2  = dppf<0x122>(term), t3  = dppf<0x123>(term);
    float t4  = dppf<0x124>(term), t5  = dppf<0x125>(term), t6  = dppf<0x126>(term);
    float t7  = dppf<0x127>(term), t8_ = dppf<0x128>(term), t9  = dppf<0x129>(term);
    float t10 = dppf<0x12A>(term), t11 = dppf<0x12B>(term), t12 = dppf<0x12C>(term);
    float t13 = dppf<0x12D>(term), t14 = dppf<0x12E>(term), t15 = dppf<0x12F>(term);
    float pm = fmax3(fmax3(fmax3(term, t1, t2), fmax3(t3, t4, t5), fmax3(t6, t7, t8_)),
                     fmax3(t9, t10, t11), fmax3(fmax3(t12, t13, t14), t15, FNINF));
    int g0  = (term == pm) ? (1 << q[0])  : 0;
    int g1  = (t1  == pm) ? (1 << q[1])  : 0;
    int g2  = (t2  == pm) ? (1 << q[2])  : 0;
    int g3  = (t3  == pm) ? (1 << q[3])  : 0;
    int g4  = (t4  == pm) ? (1 << q[4])  : 0;
    int g5  = (t5  == pm) ? (1 << q[5])  : 0;
    int g6  = (t6  == pm) ? (1 << q[6])  : 0;
    int g7  = (t7  == pm) ? (1 << q[7])  : 0;
    int g8  = (t8_ == pm) ? (1 << q[8])  : 0;
    int g9  = (t9  == pm) ? (1 << q[9])  : 0;
    int g10 = (t10 == pm) ? (1 << q[10]) : 0;
    int g11 = (t11 == pm) ? (1 << q[11]) : 0;
    int g12 = (t12 == pm) ? (1 << q[12]) : 0;
    int g13 = (t13 == pm) ? (1 << q[13]) : 0;
    int g14 = (t14 == pm) ? (1 << q[14]) : 0;
    int g15 = (t15 == pm) ? (1 << q[15]) : 0;
    int gb = (((g0|g1|g2) | (g3|g4|g5)) | ((g6|g7|g8) | (g9|g10|g11))) | (((g12|g13|g14) | g15));
    int bidx = __builtin_ctz(gb);

    if (c == 0 && h == 0) {
        score[b]    = pm;
        bestlast[b] = bidx;
    }
}

// ---------------- bt phase A: per (batch, 16-step chunk) compose map for all 10 entry tags ----------------
__global__ void __launch_bounds__(256) bt_maps(const uint2* __restrict__ bptr,
                                               const int* __restrict__ lengths,
                                               uint2* __restrict__ gmap) {
    const int c = blockIdx.x >> 4;                          // 0..127
    const int b = ((blockIdx.x & 15) << 8) + threadIdx.x;   // 0..4095
    const int len = lengths[b];
    const int r0 = c * 16 + 1;

    uint2 W[16];
    #pragma unroll
    for (int u = 0; u < 16; ++u) {
        int r = r0 + u;
        uint2 v = make_uint2(0x76543210u, 0x00000098u);     // identity map
        if (r < len) v = bptr[(size_t)r * B_N + b];
        W[u] = v;
    }

    unsigned gx = 0, gy = 0;
    #pragma unroll
    for (int e = 0; e < T_N; ++e) {
        int cur = e;
        #pragma unroll
        for (int u = 15; u >= 0; --u) cur = bpapply(W[u], cur);
        if (e < 8) gx |= (unsigned)cur << (4 * e);
        else       gy |= (unsigned)cur << (4 * (e - 8));
    }
    gmap[(size_t)c * B_N + b] = make_uint2(gx, gy);
}

// ---------------- bt phase B: compose 128 chunk maps per batch, record entry tag per chunk ----------------
__global__ void __launch_bounds__(256) bt_compose(const uint2* __restrict__ gmap,
                                                  const int* __restrict__ bestlast,
                                                  unsigned char* __restrict__ entry) {
    const int b = blockIdx.x * 256 + threadIdx.x;
    int st = bestlast[b];

    uint2 wA[16], wB[16];
    auto pre = [&](uint2 (&W)[16], int cb) {
        #pragma unroll
        for (int u = 0; u < 16; ++u) W[u] = gmap[(size_t)(cb * 16 + u) * B_N + b];
    };
    auto proc = [&](uint2 (&W)[16], int cb) {
        #pragma unroll
        for (int u = 15; u >= 0; --u) {
            int c = cb * 16 + u;
            entry[(size_t)c * B_N + b] = (unsigned char)st;
            st = bpapply(W[u], st);
        }
    };
    pre(wA, 7);
    pre(wB, 6); proc(wA, 7);
    pre(wA, 5); proc(wB, 6);
    pre(wB, 4); proc(wA, 5);
    pre(wA, 3); proc(wB, 4);
    pre(wB, 2); proc(wA, 3);
    pre(wA, 1); proc(wB, 2);
    pre(wB, 0); proc(wA, 1);
    proc(wB, 0);
}

// ---------------- bt phase C: per (batch, chunk) re-follow 16 steps from entry tag, emit path ----------------
__global__ void __launch_bounds__(256) bt_emit(const uint2* __restrict__ bptr,
                                               const int* __restrict__ lengths,
                                               const unsigned char* __restrict__ entry,
                                               float* __restrict__ opaths) {
    const int c = blockIdx.x >> 4;
    const int b = ((blockIdx.x & 15) << 8) + threadIdx.x;
    const int len = lengths[b];
    const int r0 = c * 16 + 1;

    uint2 W[16];
    #pragma unroll
    for (int u = 0; u < 16; ++u) {
        int r = r0 + u;
        uint2 v = make_uint2(0x76543210u, 0x00000098u);
        if (r < len) v = bptr[(size_t)r * B_N + b];
        W[u] = v;
    }

    int cur = entry[(size_t)c * B_N + b];
    float buf[16];
    #pragma unroll
    for (int u = 15; u >= 0; --u) {
        cur = bpapply(W[u], cur);
        buf[u] = (c * 16 + u < len) ? (float)cur : 0.0f;
    }
    float* op = opaths + (size_t)b * S_LEN + c * 16;
    #pragma unroll
    for (int qq = 0; qq < 4; ++qq) {
        *(float4*)(op + qq * 4) = make_float4(buf[qq*4+0], buf[qq*4+1], buf[qq*4+2], buf[qq*4+3]);
    }
}

extern "C" void kernel_launch(void* const* d_in, const int* in_sizes, int n_in,
                              void* d_out, int out_size, void* d_ws, size_t ws_size,
                              hipStream_t stream) {
    const float* feats   = (const float*)d_in[0];
    const float* trans   = (const float*)d_in[1];
    const int*   lengths = (const int*)d_in[2];
    float* out = (float*)d_out;

    // workspace layout
    unsigned char* bp    = (unsigned char*)d_ws;                                   // 67,108,864 B
    uint2*         gmap  = (uint2*)((char*)d_ws + (size_t)S_LEN * B_N * 8);        //  4,194,304 B
    unsigned char* entry = (unsigned char*)((char*)gmap + (size_t)(S_LEN/16) * B_N * 8); // 524,288 B
    int*           bestlast = (int*)((char*)entry + (size_t)(S_LEN/16) * B_N);     //     16,384 B

    viterbi_fwd<<<B_N / 8, 256, 0, stream>>>(feats, trans, lengths, bp, bestlast, out);
    bt_maps   <<<(S_LEN/16) * (B_N/256), 256, 0, stream>>>((const uint2*)bp, lengths, gmap);
    bt_compose<<<B_N / 256, 256, 0, stream>>>(gmap, bestlast, entry);
    bt_emit   <<<(S_LEN/16) * (B_N/256), 256, 0, stream>>>((const uint2*)bp, lengths, entry, out + B_N);
}

// Round 5
// 466.354 us; speedup vs baseline: 3.0870x; 1.1223x over previous
//
#include <hip/hip_runtime.h>
#include <stdint.h>
#include <stddef.h>

#define S_LEN 2048
#define B_N   4096
#define T_N   10
#define NEG_INF_F (-10000.0f)

template<int CTRL>
__device__ __forceinline__ int dppi(int v) {
    return __builtin_amdgcn_update_dpp(0, v, CTRL, 0xF, 0xF, true);
}
template<int CTRL>
__device__ __forceinline__ float dppf(float v) {
    return __int_as_float(dppi<CTRL>(__float_as_int(v)));
}

static __device__ __forceinline__ int imin(int a, int b) { return a < b ? a : b; }
static __device__ __forceinline__ int imax(int a, int b) { return a > b ? a : b; }
static __device__ __forceinline__ float fmax3(float a, float b, float c) { return fmaxf(fmaxf(a, b), c); }

// ---------------- F: value-only forward. 16 lanes/batch, 4 batches/wave. ----------------
// Fused rot+add via v_add_f32_dpp; stores fv checkpoints every 16 steps + terminal score.
__global__ void __launch_bounds__(256) viterbi_fwd(const float* __restrict__ feats,
                                                   const float* __restrict__ trans,
                                                   const int* __restrict__ lengths,
                                                   float* __restrict__ ckpt,     // [128][B][10] f32
                                                   int* __restrict__ bestlast,
                                                   float* __restrict__ score) {
    const float FNINF = __int_as_float(0xff800000);   // -inf
    const int tid = threadIdx.x;
    const int t   = tid & 15;
    const int b   = blockIdx.x * 16 + (tid >> 4);
    const bool act = (t < T_N);
    const int len = lengths[b];
    const int lenm1 = len - 1;

    // wave-uniform loop bound
    int lenW = len;
    lenW = imax(lenW, __shfl_xor(lenW, 16, 64));
    lenW = imax(lenW, __shfl_xor(lenW, 32, 64));
    lenW = __builtin_amdgcn_readfirstlane(lenW);

    // probe actual DPP ror source columns (direction-agnostic)
    int q[16];
    q[0]  = t;
    q[1]  = dppi<0x121>(t);  q[2]  = dppi<0x122>(t);  q[3]  = dppi<0x123>(t);
    q[4]  = dppi<0x124>(t);  q[5]  = dppi<0x125>(t);  q[6]  = dppi<0x126>(t);
    q[7]  = dppi<0x127>(t);  q[8]  = dppi<0x128>(t);  q[9]  = dppi<0x129>(t);
    q[10] = dppi<0x12A>(t);  q[11] = dppi<0x12B>(t);  q[12] = dppi<0x12C>(t);
    q[13] = dppi<0x12D>(t);  q[14] = dppi<0x12E>(t);  q[15] = dppi<0x12F>(t);

    float trr[16], tv[16];
    int bitp[16];
    #pragma unroll
    for (int r = 0; r < 16; ++r) {
        bool v = act && (q[r] < T_N);
        trr[r] = v ? trans[t * T_N + q[r]] : FNINF;   // tr[t][p_r]
        tv[r]  = v ? 0.0f : FNINF;
        bitp[r] = 1 << q[r];
    }
    const float trs = act ? trans[9 * T_N + t] : 0.0f;   // STOP row entry t

    float lastv = NEG_INF_F;

    const float* fptr = feats + (size_t)b * T_N + imin(t, T_N - 1);
    auto ldfeat = [&](int s) -> float {
        return fptr[(size_t)imin(s, S_LEN - 1) * (B_N * T_N)];
    };

    float fA[8], fB[8];
    #pragma unroll
    for (int u = 0; u < 8; ++u) fA[u] = ldfeat(u);

    // fvr init via asm (s_nop covers VALU->DPP hazard on first step)
    float fvr;
    {
        float finit = (t == 8) ? 0.0f : NEG_INF_F;
        asm("v_mov_b32 %0, %1\n\ts_nop 1" : "=v"(fvr) : "v"(finit));
    }

    for (int s0 = 0; s0 < lenW; s0 += 8) {
        #pragma unroll
        for (int u = 0; u < 8; ++u) fB[u] = ldfeat(s0 + 8 + u);

        #pragma unroll
        for (int u = 0; u < 8; ++u) {
            const int s = s0 + u;
            float cd[16];
            cd[0] = fvr + trr[0];
#define DPPADD(N, S) asm("v_add_f32_dpp %0, %1, %2 " S " row_mask:0xf bank_mask:0xf" \
                         : "=v"(cd[N]) : "v"(fvr), "v"(trr[N]))
            DPPADD(1,  "row_ror:1");  DPPADD(2,  "row_ror:2");  DPPADD(3,  "row_ror:3");
            DPPADD(4,  "row_ror:4");  DPPADD(5,  "row_ror:5");  DPPADD(6,  "row_ror:6");
            DPPADD(7,  "row_ror:7");  DPPADD(8,  "row_ror:8");  DPPADD(9,  "row_ror:9");
            DPPADD(10, "row_ror:10"); DPPADD(11, "row_ror:11"); DPPADD(12, "row_ror:12");
            DPPADD(13, "row_ror:13"); DPPADD(14, "row_ror:14"); DPPADD(15, "row_ror:15");
#undef DPPADD
            float x0 = fmax3(cd[0],  cd[1],  cd[2]);
            float x1 = fmax3(cd[3],  cd[4],  cd[5]);
            float x2 = fmax3(cd[6],  cd[7],  cd[8]);
            float x3 = fmax3(cd[9],  cd[10], cd[11]);
            float x4 = fmax3(cd[12], cd[13], cd[14]);
            float mm = fmaxf(fmax3(x0, x1, x2), fmax3(x3, x4, cd[15]));
            float f  = fA[u];
            // nv add + s_nop (covers next step's DPP read of fvr)
            asm("v_add_f32 %0, %1, %2\n\ts_nop 1" : "=v"(fvr) : "v"(mm), "v"(f));
            lastv = (s == lenm1) ? fvr : lastv;
        }

        // checkpoint fv_all[s0+8] every 16 rows
        if (((s0 + 8) & 15) == 0) {
            const int cc = (s0 + 8) >> 4;
            if (act && (s0 + 8) <= len)
                ckpt[((size_t)cc * B_N + b) * T_N + t] = fvr;
        }

        #pragma unroll
        for (int u = 0; u < 8; ++u) fA[u] = fB[u];
    }

    // terminal: term[tag] = last_fv[tag] + trans[STOP][tag]
    float term = act ? (lastv + trs) : FNINF;
    float t1  = dppf<0x121>(term), t2  = dppf<0x122>(term), t3  = dppf<0x123>(term);
    float t4  = dppf<0x124>(term), t5  = dppf<0x125>(term), t6  = dppf<0x126>(term);
    float t7  = dppf<0x127>(term), t8_ = dppf<0x128>(term), t9  = dppf<0x129>(term);
    float t10 = dppf<0x12A>(term), t11 = dppf<0x12B>(term), t12 = dppf<0x12C>(term);
    float t13 = dppf<0x12D>(term), t14 = dppf<0x12E>(term), t15 = dppf<0x12F>(term);
    float pm = fmax3(fmax3(fmax3(term, t1, t2), fmax3(t3, t4, t5), fmax3(t6, t7, t8_)),
                     fmax3(t9, t10, t11), fmax3(fmax3(t12, t13, t14), t15, FNINF));
    int g0  = (term == pm) ? (1 << q[0])  : 0;
    int g1  = (t1  == pm) ? (1 << q[1])  : 0;
    int g2  = (t2  == pm) ? (1 << q[2])  : 0;
    int g3  = (t3  == pm) ? (1 << q[3])  : 0;
    int g4  = (t4  == pm) ? (1 << q[4])  : 0;
    int g5  = (t5  == pm) ? (1 << q[5])  : 0;
    int g6  = (t6  == pm) ? (1 << q[6])  : 0;
    int g7  = (t7  == pm) ? (1 << q[7])  : 0;
    int g8  = (t8_ == pm) ? (1 << q[8])  : 0;
    int g9  = (t9  == pm) ? (1 << q[9])  : 0;
    int g10 = (t10 == pm) ? (1 << q[10]) : 0;
    int g11 = (t11 == pm) ? (1 << q[11]) : 0;
    int g12 = (t12 == pm) ? (1 << q[12]) : 0;
    int g13 = (t13 == pm) ? (1 << q[13]) : 0;
    int g14 = (t14 == pm) ? (1 << q[14]) : 0;
    int g15 = (t15 == pm) ? (1 << q[15]) : 0;
    int gb = (((g0|g1|g2) | (g3|g4|g5)) | ((g6|g7|g8) | (g9|g10|g11))) | ((g12|g13|g14) | g15);
    int bidx = __builtin_ctz(gb);

    if (t == 0) {
        score[b]    = pm;
        bestlast[b] = bidx;
    }
}

// ---------------- A: parallel argmax recompute per (batch, 16-chunk) ----------------
// From checkpoint fv_all[c*16], recompute 16 steps; per step store 10-tag nibble map
// (bpd: tags 0-7 dword, bpb: tags 8-9 byte) and compose the chunk map -> gmap.
__global__ void __launch_bounds__(256) bt_maps(const float* __restrict__ feats,
                                               const float* __restrict__ trans,
                                               const int* __restrict__ lengths,
                                               const float* __restrict__ ckpt,
                                               unsigned* __restrict__ bpd,
                                               unsigned char* __restrict__ bpb,
                                               uint2* __restrict__ gmap) {
    const int c = blockIdx.x >> 4;                          // 0..127
    const int b = ((blockIdx.x & 15) << 8) + threadIdx.x;   // 0..4095
    const int len = lengths[b];
    const int r0 = c * 16;

    float fv[10];
    if (c == 0) {
        #pragma unroll
        for (int p = 0; p < 10; ++p) fv[p] = (p == 8) ? 0.0f : NEG_INF_F;
    } else {
        #pragma unroll
        for (int p = 0; p < 10; ++p) fv[p] = ckpt[((size_t)c * B_N + b) * T_N + p];
    }

    unsigned Glo = 0x76543210u, Ghi = 0x98u;   // identity map

    #pragma unroll
    for (int k = 0; k <= 16; ++k) {
        const int r = r0 + k;
        float m[10]; int idx[10];
        #pragma unroll
        for (int n = 0; n < 10; ++n) {
            float cd[10];
            #pragma unroll
            for (int p = 0; p < 10; ++p) cd[p] = fv[p] + trans[n * T_N + p];
            float x0 = fmax3(cd[0], cd[1], cd[2]);
            float x1 = fmax3(cd[3], cd[4], cd[5]);
            float x2 = fmax3(cd[6], cd[7], cd[8]);
            float mm = fmaxf(fmax3(x0, x1, x2), cd[9]);
            m[n] = mm;
            if (k >= 1) {
                int ix = 9;
                #pragma unroll
                for (int p = 8; p >= 0; --p) ix = (cd[p] == mm) ? p : ix;   // first tie = min p
                idx[n] = ix;
            }
        }
        if (k >= 1) {
            unsigned mlo = 0, mhi = 0, nGlo = 0, nGhi = 0;
            unsigned long long G64 = ((unsigned long long)Ghi << 32) | Glo;
            #pragma unroll
            for (int n = 0; n < 10; ++n) {
                unsigned nib = (unsigned)(G64 >> (idx[n] * 4)) & 15u;
                if (n < 8) { mlo |= (unsigned)idx[n] << (4 * n);       nGlo |= nib << (4 * n); }
                else       { mhi |= (unsigned)idx[n] << (4 * (n - 8)); nGhi |= nib << (4 * (n - 8)); }
            }
            bpd[(size_t)r * B_N + b] = mlo;
            bpb[(size_t)r * B_N + b] = (unsigned char)mhi;
            bool live = (r < len);                 // beyond len: compose identity (keep G)
            Glo = live ? nGlo : Glo;
            Ghi = live ? nGhi : Ghi;
        }
        if (k <= 15) {
            #pragma unroll
            for (int n = 0; n < 10; ++n)
                fv[n] = m[n] + feats[((size_t)r * B_N + b) * T_N + n];
        }
    }
    gmap[(size_t)c * B_N + b] = make_uint2(Glo, Ghi);
}

// nibble-map apply: next = (w64 >> 4*cur) & 15
static __device__ __forceinline__ int bpapply(uint2 w, int cur) {
    unsigned long long w64 = ((unsigned long long)w.y << 32) | (unsigned long long)w.x;
    return (int)((w64 >> (cur * 4)) & 15ULL);
}

// ---------------- B: compose 128 chunk maps per batch, record entry tag per chunk ----------------
__global__ void __launch_bounds__(256) bt_compose(const uint2* __restrict__ gmap,
                                                  const int* __restrict__ bestlast,
                                                  unsigned char* __restrict__ entry) {
    const int b = blockIdx.x * 256 + threadIdx.x;
    int st = bestlast[b];

    uint2 wA[16], wB[16];
    auto pre = [&](uint2 (&W)[16], int cb) {
        #pragma unroll
        for (int u = 0; u < 16; ++u) W[u] = gmap[(size_t)(cb * 16 + u) * B_N + b];
    };
    auto proc = [&](uint2 (&W)[16], int cb) {
        #pragma unroll
        for (int u = 15; u >= 0; --u) {
            int cc = cb * 16 + u;
            entry[(size_t)cc * B_N + b] = (unsigned char)st;
            st = bpapply(W[u], st);
        }
    };
    pre(wA, 7);
    pre(wB, 6); proc(wA, 7);
    pre(wA, 5); proc(wB, 6);
    pre(wB, 4); proc(wA, 5);
    pre(wA, 3); proc(wB, 4);
    pre(wB, 2); proc(wA, 3);
    pre(wA, 1); proc(wB, 2);
    pre(wB, 0); proc(wA, 1);
    proc(wB, 0);
}

// ---------------- C: follow maps per (batch, chunk) from entry tag, emit path ----------------
__global__ void __launch_bounds__(256) bt_emit(const unsigned* __restrict__ bpd,
                                               const unsigned char* __restrict__ bpb,
                                               const int* __restrict__ lengths,
                                               const unsigned char* __restrict__ entry,
                                               float* __restrict__ opaths) {
    const int c = blockIdx.x >> 4;
    const int b = ((blockIdx.x & 15) << 8) + threadIdx.x;
    const int len = lengths[b];
    const int r0 = c * 16 + 1;

    unsigned Wd[16], Wb[16];
    #pragma unroll
    for (int u = 0; u < 16; ++u) {
        int r = r0 + u;
        unsigned d = 0x76543210u, h = 0x98u;   // identity
        if (r < len) { d = bpd[(size_t)r * B_N + b]; h = bpb[(size_t)r * B_N + b]; }
        Wd[u] = d; Wb[u] = h;
    }

    int cur = entry[(size_t)c * B_N + b];
    float buf[16];
    #pragma unroll
    for (int u = 15; u >= 0; --u) {
        unsigned long long w = ((unsigned long long)Wb[u] << 32) | Wd[u];
        cur = (int)((w >> (cur * 4)) & 15ULL);
        buf[u] = (c * 16 + u < len) ? (float)cur : 0.0f;
    }
    float* op = opaths + (size_t)b * S_LEN + c * 16;
    #pragma unroll
    for (int qq = 0; qq < 4; ++qq)
        *(float4*)(op + qq * 4) = make_float4(buf[qq*4+0], buf[qq*4+1], buf[qq*4+2], buf[qq*4+3]);
}

extern "C" void kernel_launch(void* const* d_in, const int* in_sizes, int n_in,
                              void* d_out, int out_size, void* d_ws, size_t ws_size,
                              hipStream_t stream) {
    const float* feats   = (const float*)d_in[0];
    const float* trans   = (const float*)d_in[1];
    const int*   lengths = (const int*)d_in[2];
    float* out = (float*)d_out;

    // workspace layout (~67.7 MB total; 71.8 MB was proven available in prior rounds)
    char* w = (char*)d_ws;
    float*         ckpt  = (float*)w;                 w += (size_t)128 * B_N * T_N * 4;   // 20,971,520
    unsigned*      bpd   = (unsigned*)w;              w += (size_t)(S_LEN + 1) * B_N * 4; // 33,570,816
    unsigned char* bpb   = (unsigned char*)w;         w += (size_t)(S_LEN + 1) * B_N;     //  8,392,704
    uint2*         gmap  = (uint2*)w;                 w += (size_t)(S_LEN / 16) * B_N * 8;//  4,194,304
    unsigned char* entry = (unsigned char*)w;         w += (size_t)(S_LEN / 16) * B_N;    //    524,288
    int*           bestlast = (int*)w;

    viterbi_fwd<<<B_N / 16, 256, 0, stream>>>(feats, trans, lengths, ckpt, bestlast, out);
    bt_maps   <<<(S_LEN / 16) * (B_N / 256), 256, 0, stream>>>(feats, trans, lengths, ckpt, bpd, bpb, gmap);
    bt_compose<<<B_N / 256, 256, 0, stream>>>(gmap, bestlast, entry);
    bt_emit   <<<(S_LEN / 16) * (B_N / 256), 256, 0, stream>>>(bpd, bpb, lengths, entry, out + B_N);
}